// Round 1
// baseline (105.429 us; speedup 1.0000x reference)
//
#include <hip/hip_runtime.h>

// ConvTranspose2d (C_in=256 -> C_out=128, k=4, stride=2, pad=1), x 128x128 -> out 256x256.
// out[o, 2*yo+ry, 2*xo+rx] = sum_ci sum_{a,b} X[ci, yo+ry-1+a, xo+rx-1+b] * W[o,ci,2a+ry,2b+rx] + bias[o]
// Implemented as bf16 MFMA (32x32x16), 4 parity classes, K-split across wave pairs.

typedef __attribute__((ext_vector_type(8))) short bf16x8;
typedef __attribute__((ext_vector_type(16))) float f32x16;

#define CI 256
#define CO 128
#define HW 128
#define YO_TILE 4
#define XO_TILE 16
#define CELLS_R 6               // yo rows needed: Y0-1 .. Y0+4
#define CELLS_C 18              // xo cols needed: X0-1 .. X0+16
#define NCELLS (CELLS_R * CELLS_C)   // 108 cells, each 256 ci * 2B = 512B
#define LDS_BYTES (NCELLS * 512)     // 55296 B

static __device__ __forceinline__ unsigned short f2bf(float f) {
  union { float f; unsigned u; } v; v.f = f;
  return (unsigned short)((v.u + 0x7FFFu + ((v.u >> 16) & 1u)) >> 16);  // RTNE
}

// ---- Pass 1a: x[ci][h][w] f32  ->  xbT[h*128+w][ci] bf16 (tiled transpose) ----
__global__ void transpose_x_kernel(const float* __restrict__ x,
                                   unsigned short* __restrict__ xbT) {
  __shared__ float tile[32][33];
  const int hw0 = blockIdx.x * 32;
  const int ci0 = blockIdx.y * 32;
  const int tx = threadIdx.x;   // 0..31
  const int ty = threadIdx.y;   // 0..7
#pragma unroll
  for (int i = 0; i < 4; ++i) {
    const int ci = ci0 + ty + i * 8;
    tile[ty + i * 8][tx] = x[ci * (HW * HW) + hw0 + tx];
  }
  __syncthreads();
#pragma unroll
  for (int i = 0; i < 4; ++i) {
    const int hw = hw0 + ty + i * 8;
    xbT[hw * CI + ci0 + tx] = f2bf(tile[tx][ty + i * 8]);
  }
}

// ---- Pass 1b: W[o][ci][kh][kw] f32 -> Wb[((tap*16 + cbG)*128 + o)*16 + ci_lo] bf16 ----
// tap = kh*4+kw; ci = cbG*16 + ci_lo.  A-fragment = 16B contiguous per lane, wave-coalesced.
__global__ void reorg_w_kernel(const float* __restrict__ W,
                               unsigned short* __restrict__ Wb) {
  const int tid = blockIdx.x * 256 + threadIdx.x;   // 0 .. 524287
  const int ci_lo = tid & 15;
  const int o     = (tid >> 4) & 127;
  const int cbG   = (tid >> 11) & 15;
  const int tap   = (tid >> 15) & 15;
  const int ci = cbG * 16 + ci_lo;
  Wb[tid] = f2bf(W[(o * CI + ci) * 16 + tap]);
}

// ---- Main kernel ----
// grid (8, 32) = (xo-tiles, yo-tiles), 512 threads = 8 waves.
// wave = (class = wave&3, K-half = wave>>2).  Wave tile: M=128 (4 mt of 32), N=64 (2 nt of 32).
// n (0..31) -> yo_off = n>>4 (+2*nt), xo_off = n&15.
__global__ __launch_bounds__(512, 2) void tconv_mfma_kernel(
    const unsigned short* __restrict__ xbT,
    const unsigned short* __restrict__ Wb,
    const float* __restrict__ bias,
    float* __restrict__ out) {
  __shared__ __align__(16) unsigned char LDS[LDS_BYTES];
  const int tid = threadIdx.x;
  const int X0 = blockIdx.x * XO_TILE;
  const int Y0 = blockIdx.y * YO_TILE;

  // ---- stage X tile once: cell (r,c) holds 256 ci bf16; slot s (8 ci / 16B) stored at s^c ----
  for (int e = tid; e < NCELLS * 32; e += 512) {
    const int s = e & 31;
    const int cell = e >> 5;
    const int c = cell % CELLS_C;
    const int r = cell / CELLS_C;
    const int gr = Y0 - 1 + r;
    const int gc = X0 - 1 + c;
    uint4 val = make_uint4(0u, 0u, 0u, 0u);
    if (gr >= 0 && gr < HW && gc >= 0 && gc < HW)
      val = *(const uint4*)(xbT + ((gr * HW + gc) * CI + s * 8));
    *(uint4*)(LDS + cell * 512 + ((s ^ c) * 16)) = val;
  }
  __syncthreads();

  const int lane = tid & 63;
  const int wave = tid >> 6;
  const int cls = wave & 3;
  const int ry = cls >> 1, rx = cls & 1;
  const int kh2 = wave >> 2;          // K-half: ci in [kh2*128, kh2*128+128)
  const int l31 = lane & 31;
  const int lhi = lane >> 5;          // k sub-group: k = lhi*8 + j
  const int nrow = l31 >> 4;          // spatial: yo offset within n-tile
  const int ncol = l31 & 15;          // spatial: xo offset

  f32x16 acc[4][2];
#pragma unroll
  for (int mt = 0; mt < 4; ++mt)
#pragma unroll
    for (int nt = 0; nt < 2; ++nt)
#pragma unroll
      for (int t = 0; t < 16; ++t) acc[mt][nt][t] = 0.0f;

  // ---- K loop: 4 taps x 8 ci-chunks(16) ; no barriers ----
#pragma unroll
  for (int a = 0; a < 2; ++a) {
#pragma unroll
    for (int b = 0; b < 2; ++b) {
      const int tap = (2 * a + ry) * 4 + (2 * b + rx);
      const int c_l = ncol + rx + b;          // 0..17
      const int r_base = nrow + ry + a;       // +2*nt -> 0..5
      const unsigned short* wtap = Wb + tap * 16 * 2048;
#pragma unroll
      for (int cb = 0; cb < 8; ++cb) {
        const int cbG = kh2 * 8 + cb;         // global ci chunk (16 ci)
        const int s_idx = cbG * 2 + lhi;      // 8-ci slot index 0..31
        bf16x8 bfrag[2];
#pragma unroll
        for (int nt = 0; nt < 2; ++nt) {
          const int cell = (r_base + 2 * nt) * CELLS_C + c_l;
          bfrag[nt] = *(const bf16x8*)(LDS + cell * 512 + ((s_idx ^ c_l) * 16));
        }
        const unsigned short* wk = wtap + cbG * 2048 + l31 * 16 + lhi * 8;
#pragma unroll
        for (int mt = 0; mt < 4; ++mt) {
          const bf16x8 afrag = *(const bf16x8*)(wk + mt * 512);
#pragma unroll
          for (int nt = 0; nt < 2; ++nt)
            acc[mt][nt] = __builtin_amdgcn_mfma_f32_32x32x16_bf16(
                afrag, bfrag[nt], acc[mt][nt], 0, 0, 0);
        }
      }
    }
  }

  // ---- K-split reduction (reuse LDS, 4 rounds of 32KB) + store ----
  __syncthreads();
  float* red = (float*)LDS;
#pragma unroll
  for (int round = 0; round < 4; ++round) {
    const int nt = round >> 1;
    const int oh = round & 1;
    if (kh2 == 1) {
#pragma unroll
      for (int m2 = 0; m2 < 2; ++m2) {
        const f32x16 v = acc[oh * 2 + m2][nt];
#pragma unroll
        for (int t = 0; t < 16; ++t) {
          const int o_l = m2 * 32 + (t & 3) + 4 * lhi + 8 * (t >> 2);
          red[(cls * 64 + o_l) * 32 + l31] = v[t];
        }
      }
    }
    __syncthreads();
    if (kh2 == 0) {
#pragma unroll
      for (int m2 = 0; m2 < 2; ++m2) {
        const f32x16 v = acc[oh * 2 + m2][nt];
#pragma unroll
        for (int t = 0; t < 16; ++t) {
          const int rowD = (t & 3) + 4 * lhi + 8 * (t >> 2);
          const int o_l = m2 * 32 + rowD;
          const int o = oh * 64 + o_l;
          const float sum = v[t] + red[(cls * 64 + o_l) * 32 + l31] + bias[o];
          const int yo = Y0 + nt * 2 + nrow;
          const int xo = X0 + ncol;
          const int y = 2 * yo + ry;
          const int xg = 2 * xo + rx;
          out[((size_t)o << 16) + (y << 8) + xg] = sum;
        }
      }
    }
    __syncthreads();
  }
}

extern "C" void kernel_launch(void* const* d_in, const int* in_sizes, int n_in,
                              void* d_out, int out_size, void* d_ws, size_t ws_size,
                              hipStream_t stream) {
  const float* x = (const float*)d_in[0];     // (256,128,128)
  const float* W = (const float*)d_in[1];     // (128,256,4,4)
  const float* b = (const float*)d_in[2];     // (128,)
  float* out = (float*)d_out;                 // (128,256,256)

  unsigned short* xbT = (unsigned short*)d_ws;            // 8 MB
  unsigned short* Wb = xbT + (size_t)CI * HW * HW;        // 1 MB

  transpose_x_kernel<<<dim3((HW * HW) / 32, CI / 32), dim3(32, 8), 0, stream>>>(x, xbT);
  reorg_w_kernel<<<dim3((16 * 16 * CO * 16) / 256), dim3(256), 0, stream>>>(W, Wb);
  tconv_mfma_kernel<<<dim3(HW / XO_TILE, HW / YO_TILE), dim3(512), 0, stream>>>(xbT, Wb, b, out);
}